// Round 3
// baseline (7921.685 us; speedup 1.0000x reference)
//
#include <hip/hip_runtime.h>
#include <math.h>

// Problem constants
#define B_   64
#define P_   196      // 14*14 pixels
#define E_   2048
#define L_   30
#define T_   29       // L-1 decode steps
#define V_   10000
#define EMB_ 512
#define AML_ 768
#define ADL_ 500
#define D_   1012     // 512+ADL
#define A_   1012
#define G4_  4048     // 4*D
#define XK_  2560     // EMB+E

typedef unsigned short u16;
typedef __attribute__((ext_vector_type(8))) short bf16x8;
typedef __attribute__((ext_vector_type(4))) float f32x4;

__device__ __forceinline__ float sigf(float x) { return 1.f / (1.f + __expf(-x)); }
__device__ __forceinline__ float tanhf_fast(float x) { return 1.f - 2.f / (__expf(2.f * x) + 1.f); }
__device__ __forceinline__ u16 f2bf(float f) {
    unsigned u = __float_as_uint(f);
    return (u16)((u + 0x7FFFu + ((u >> 16) & 1u)) >> 16);
}
__device__ __forceinline__ float bf2f(u16 v) { return __uint_as_float(((unsigned)v) << 16); }

// ---------------- setup: stable descending argsort + masks + int outputs ----------------
__global__ void k_setup(const int* __restrict__ clen, const int* __restrict__ caps,
                        float* __restrict__ out_caps, float* __restrict__ out_dlens,
                        float* __restrict__ out_sind,
                        int* __restrict__ sort_ind, int* __restrict__ dlens_i,
                        int* __restrict__ nact, int* __restrict__ caps_s)
{
    __shared__ int lens[B_];
    int t = threadIdx.x;
    if (t < B_) lens[t] = clen[t];
    __syncthreads();
    if (t < B_) {
        int my = lens[t];
        int rank = 0;
        for (int j = 0; j < B_; ++j) {
            int lj = lens[j];
            if (lj > my || (lj == my && j < t)) rank++;  // stable descending
        }
        sort_ind[rank] = t;
    }
    __syncthreads();
    if (t < B_) {
        int orig = sort_ind[t];
        int dl = lens[orig] - 1;
        dlens_i[t] = dl;
        out_dlens[t] = (float)dl;
        out_sind[t] = (float)orig;
        for (int j = 0; j < L_; ++j) {
            int cv = caps[orig * L_ + j];
            caps_s[t * L_ + j] = cv;
            out_caps[t * L_ + j] = (float)cv;
        }
    }
    __syncthreads();
    if (t < T_) {
        int cnt = 0;
        for (int j = 0; j < B_; ++j) cnt += (dlens_i[j] > t) ? 1 : 0;
        nact[t] = cnt;
    }
}

// ---------------- zero entire output buffer ----------------
__global__ void k_zero(float4* __restrict__ p, long n4)
{
    long i = (long)blockIdx.x * 256 + threadIdx.x;
    if (i < n4) p[i] = make_float4(0.f, 0.f, 0.f, 0.f);
}

// ---------------- gather + fp32->bf16 convert enc rows into sorted order ----------------
__global__ void k_cvt_enc(const float* __restrict__ enc, const int* __restrict__ sort_ind,
                          u16* __restrict__ A_bf)
{
    int row = blockIdx.y;                 // 0..12543  (b*196+p sorted)
    int b = row / 196, p = row - b * 196;
    int e4 = (blockIdx.x * 256 + threadIdx.x) * 4;   // 0..2044
    const float* src = enc + ((long)sort_ind[b] * 196 + p) * E_ + e4;
    float4 v = *(const float4*)src;
    unsigned lo = (unsigned)f2bf(v.x) | ((unsigned)f2bf(v.y) << 16);
    unsigned hi = (unsigned)f2bf(v.z) | ((unsigned)f2bf(v.w) << 16);
    uint2 pk; pk.x = lo; pk.y = hi;
    *(uint2*)(A_bf + (long)row * E_ + e4) = pk;
}

// ---------------- tiled transpose + convert: src fp32 [K][N] -> dst bf16 [Np][Kp] (pads=0) ----
__global__ void k_transpose(const float* __restrict__ src, u16* __restrict__ dst,
                            int K, int N, int Kp, int Np)
{
    __shared__ float tile[32][33];
    int n0 = blockIdx.x * 32, k0 = blockIdx.y * 32;
    int tx = threadIdx.x, ty = threadIdx.y;   // (32,8)
    for (int r = ty; r < 32; r += 8) {
        int k = k0 + r, n = n0 + tx;
        tile[r][tx] = (k < K && n < N) ? src[(long)k * N + n] : 0.f;
    }
    __syncthreads();
    for (int r = ty; r < 32; r += 8) {
        int n = n0 + r, k = k0 + tx;
        if (n < Np && k < Kp) dst[(long)n * Kp + k] = f2bf(tile[tx][r]);
    }
}

// ---------------- enc mean -> dec_in_bf cols [0,2048) ----------------
__global__ void k_encmean(const float* __restrict__ enc, const int* __restrict__ sort_ind,
                          u16* __restrict__ dec_in)
{
    int b = blockIdx.y;
    int e = blockIdx.x * 256 + threadIdx.x;   // < 2048
    int orig = sort_ind[b];
    const float* src = enc + (long)orig * P_ * E_ + e;
    float s = 0.f;
    for (int p = 0; p < P_; ++p) s += src[(long)p * E_];
    dec_in[(long)b * XK_ + e] = f2bf(s * (1.f / 196.f));
}

// ---------------- context = arts @ W_par + b_par -> dec_in_bf cols [2048,2560), pad 0 ----
__global__ void k_ctx(const float* __restrict__ arts, const float* __restrict__ W_par,
                      const float* __restrict__ b_par, const int* __restrict__ sort_ind,
                      u16* __restrict__ dec_in)
{
    int b = blockIdx.y;
    int k = blockIdx.x * 256 + threadIdx.x;   // < 512
    if (k >= 512) return;
    float s = 0.f;
    if (k < ADL_) {
        int orig = sort_ind[b];
        const float* ar = arts + (long)orig * AML_;
        s = b_par[k];
        for (int m = 0; m < AML_; ++m) s = fmaf(ar[m], W_par[m * ADL_ + k], s);
    }
    dec_in[(long)b * XK_ + E_ + k] = f2bf(s);
}

// ---------------- att1 MFMA: A_bf[12544][2048] @ WT_enc[1024][2048]^T -> att1_bf[12544][1024]
__global__ void __launch_bounds__(256) k_att1_mfma(
    const u16* __restrict__ A, const u16* __restrict__ W,
    const float* __restrict__ bias, u16* __restrict__ Yb)
{
    int w = threadIdx.x >> 6, lane = threadIdx.x & 63;
    int lr = lane & 15, lk = (lane >> 4) * 8;
    int n0 = blockIdx.x * 256 + w * 64;     // wave n-stripe (4 x 16)
    int r0 = blockIdx.y * 64;               // block m-stripe (4 x 16)
    f32x4 acc[4][4];
#pragma unroll
    for (int i = 0; i < 4; ++i)
#pragma unroll
        for (int j = 0; j < 4; ++j) acc[i][j] = (f32x4){0.f, 0.f, 0.f, 0.f};
    const u16* ap = A + (long)(r0 + lr) * E_ + lk;
    const u16* wp = W + (long)(n0 + lr) * E_ + lk;
    for (int k = 0; k < E_; k += 32) {
        bf16x8 af[4], bf[4];
#pragma unroll
        for (int mt = 0; mt < 4; ++mt) af[mt] = *(const bf16x8*)(ap + (long)mt * 16 * E_ + k);
#pragma unroll
        for (int nt = 0; nt < 4; ++nt) bf[nt] = *(const bf16x8*)(wp + (long)nt * 16 * E_ + k);
#pragma unroll
        for (int mt = 0; mt < 4; ++mt)
#pragma unroll
            for (int nt = 0; nt < 4; ++nt)
                acc[mt][nt] = __builtin_amdgcn_mfma_f32_16x16x32_bf16(af[mt], bf[nt], acc[mt][nt], 0, 0, 0);
    }
#pragma unroll
    for (int mt = 0; mt < 4; ++mt) {
#pragma unroll
        for (int nt = 0; nt < 4; ++nt) {
            int n = n0 + nt * 16 + lr;
            float bv = (n < A_) ? bias[n] : 0.f;
#pragma unroll
            for (int j = 0; j < 4; ++j) {
                int row = r0 + mt * 16 + (lane >> 4) * 4 + j;
                u16 outv = (n < A_) ? f2bf(acc[mt][nt][j] + bv) : (u16)0;  // zero pad cols
                Yb[(long)row * 1024 + n] = outv;
            }
        }
    }
}

// ---------------- skinny MFMA: Y[64][N] = act(A1[64][K1]@W1^T + b1), optional bf16 out ----
// OUT: 0 = f32, 1 = bf16.  PADZ: write 0 for n in [Nmax, gridN)
template <int ACT, int OUT, int PADZ>
__global__ void __launch_bounds__(256) k_skinny(
    const u16* __restrict__ A1, const u16* __restrict__ W1, int K1,
    const float* __restrict__ bias1, void* __restrict__ Yv,
    long ldY, long offY, int Nmax,
    const int* __restrict__ nact, int t)
{
    int Bact = (t >= 0) ? nact[t] : B_;
    if (Bact <= 0) return;
    int mmax = (Bact + 15) >> 4;
    int w = threadIdx.x >> 6, lane = threadIdx.x & 63;
    int lr = lane & 15, lk = (lane >> 4) * 8;
    int n0 = blockIdx.x * 64 + w * 16;
    f32x4 acc[4];
#pragma unroll
    for (int m = 0; m < 4; ++m) acc[m] = (f32x4){0.f, 0.f, 0.f, 0.f};

    int n = n0 + lr;
    int nc = n < Nmax ? n : Nmax - 1;
    const u16* a1p = A1 + (long)lr * K1 + lk;
    const u16* w1p = W1 + (long)nc * K1 + lk;
    for (int k = 0; k < K1; k += 32) {
        bf16x8 bw = *(const bf16x8*)(w1p + k);
#pragma unroll
        for (int m = 0; m < 4; ++m)
            if (m < mmax) {
                bf16x8 aw = *(const bf16x8*)(a1p + (long)m * 16 * K1 + k);
                acc[m] = __builtin_amdgcn_mfma_f32_16x16x32_bf16(aw, bw, acc[m], 0, 0, 0);
            }
    }
    float bv = (n < Nmax) ? bias1[n] : 0.f;
#pragma unroll
    for (int m = 0; m < 4; ++m) {
        if (m < mmax) {
#pragma unroll
            for (int j = 0; j < 4; ++j) {
                int b = m * 16 + (lane >> 4) * 4 + j;
                if (b < Bact) {
                    float v = acc[m][j] + bv;
                    if (ACT == 1) v = sigf(v);
                    if (n < Nmax) {
                        if (OUT == 1) ((u16*)Yv)[(long)b * ldY + offY + n] = f2bf(v);
                        else          ((float*)Yv)[(long)b * ldY + offY + n] = v;
                    } else if (PADZ) {
                        if (OUT == 1) ((u16*)Yv)[(long)b * ldY + offY + n] = 0;
                        else          ((float*)Yv)[(long)b * ldY + offY + n] = 0.f;
                    }
                }
            }
        }
    }
}

// ---------------- fused att2 + fbuf: blocks 0-15 -> att2 (linear), 16-47 -> fbuf (sigmoid)
__global__ void __launch_bounds__(256) k_att2fb(
    const u16* __restrict__ h_bf, const u16* __restrict__ WT_dec,
    const u16* __restrict__ WT_fb, const float* __restrict__ b_dec,
    const float* __restrict__ b_fb, float* __restrict__ att2,
    float* __restrict__ fbuf, const int* __restrict__ nact, int t)
{
    int Bact = nact[t];
    if (Bact <= 0) return;
    int mmax = (Bact + 15) >> 4;
    int isfb = blockIdx.x >= 16;
    const u16* W = isfb ? WT_fb : WT_dec;
    const float* bias = isfb ? b_fb : b_dec;
    float* Y = isfb ? fbuf : att2;
    int Nmax = isfb ? E_ : A_;
    long ldY = isfb ? (long)E_ : 1024L;
    int nb = isfb ? blockIdx.x - 16 : blockIdx.x;

    int w = threadIdx.x >> 6, lane = threadIdx.x & 63;
    int lr = lane & 15, lk = (lane >> 4) * 8;
    int n = nb * 64 + w * 16 + lr;
    int nc = n < Nmax ? n : Nmax - 1;
    f32x4 acc[4];
#pragma unroll
    for (int m = 0; m < 4; ++m) acc[m] = (f32x4){0.f, 0.f, 0.f, 0.f};
    const u16* ap = h_bf + (long)lr * 1024 + lk;
    const u16* wp = W + (long)nc * 1024 + lk;
    for (int k = 0; k < 1024; k += 32) {
        bf16x8 bw = *(const bf16x8*)(wp + k);
#pragma unroll
        for (int m = 0; m < 4; ++m)
            if (m < mmax) {
                bf16x8 aw = *(const bf16x8*)(ap + (long)m * 16 * 1024 + k);
                acc[m] = __builtin_amdgcn_mfma_f32_16x16x32_bf16(aw, bw, acc[m], 0, 0, 0);
            }
    }
    if (n >= Nmax) return;
    float bv = bias[n];
#pragma unroll
    for (int m = 0; m < 4; ++m) {
        if (m < mmax) {
#pragma unroll
            for (int j = 0; j < 4; ++j) {
                int b = m * 16 + (lane >> 4) * 4 + j;
                if (b < Bact) {
                    float v = acc[m][j] + bv;
                    if (isfb) v = sigf(v);
                    Y[(long)b * ldY + n] = v;
                }
            }
        }
    }
}

// ---------------- fused scores + softmax: one block per b ----------------
__global__ void __launch_bounds__(256) k_attn(
    const u16* __restrict__ att1, const float* __restrict__ att2,
    const float* __restrict__ W_full, const float* __restrict__ b_full,
    float* __restrict__ alpha, float* __restrict__ alphas_out,
    const int* __restrict__ nact, int t)
{
    int b = blockIdx.x;
    if (b >= nact[t]) return;
    int tid = threadIdx.x;
    int w = tid >> 6, lane = tid & 63;
    __shared__ float sc[P_];
    __shared__ float red[4];

    // preload att2 + W_full pairs into registers (shared across 49 p)
    float2 wreg[8], a2reg[8];
    const float* a2 = att2 + (long)b * 1024;
#pragma unroll
    for (int i = 0; i < 8; ++i) {
        int j2 = lane + 64 * i;
        if (j2 < 506) {
            wreg[i] = *(const float2*)(W_full + 2 * j2);
            a2reg[i] = *(const float2*)(a2 + 2 * j2);
        } else {
            wreg[i] = make_float2(0.f, 0.f);
            a2reg[i] = make_float2(0.f, 0.f);
        }
    }
    float bf0 = b_full[0];
    for (int pi = 0; pi < 49; ++pi) {
        int p = w * 49 + pi;
        const u16* a1 = att1 + ((long)b * P_ + p) * 1024;
        float acc = 0.f;
#pragma unroll
        for (int i = 0; i < 8; ++i) {
            int j2 = lane + 64 * i;
            if (j2 < 506) {
                unsigned pk = *(const unsigned*)(a1 + 2 * j2);
                float v0 = bf2f((u16)(pk & 0xFFFF)) + a2reg[i].x;
                float v1 = bf2f((u16)(pk >> 16)) + a2reg[i].y;
                v0 = v0 > 0.f ? v0 : 0.f;
                v1 = v1 > 0.f ? v1 : 0.f;
                acc = fmaf(v0, wreg[i].x, acc);
                acc = fmaf(v1, wreg[i].y, acc);
            }
        }
        for (int m = 32; m >= 1; m >>= 1) acc += __shfl_xor(acc, m);
        if (lane == 0) sc[p] = acc + bf0;
    }
    __syncthreads();
    // softmax over 196
    float v = (tid < P_) ? sc[tid] : -1e30f;
    float m = v;
    for (int s = 32; s >= 1; s >>= 1) m = fmaxf(m, __shfl_xor(m, s));
    if (lane == 0) red[w] = m;
    __syncthreads();
    m = fmaxf(fmaxf(red[0], red[1]), fmaxf(red[2], red[3]));
    float e = (tid < P_) ? __expf(v - m) : 0.f;
    float s_ = e;
    for (int s = 32; s >= 1; s >>= 1) s_ += __shfl_xor(s_, s);
    __syncthreads();
    if (lane == 0) red[w] = s_;
    __syncthreads();
    s_ = red[0] + red[1] + red[2] + red[3];
    if (tid < P_) {
        float a = e / s_;
        alpha[b * P_ + tid] = a;
        alphas_out[((long)b * T_ + t) * P_ + tid] = a;
    }
}

// ---------------- awe (weighted enc sum from A_bf) * gate + emb gather -> x_bf [b][2560] ----
__global__ void k_awe_x(const u16* __restrict__ A_bf,
                        const float* __restrict__ alpha, const float* __restrict__ fbuf,
                        const float* __restrict__ E_emb, const int* __restrict__ caps_s,
                        u16* __restrict__ x_bf, const int* __restrict__ nact, int t)
{
    int b = blockIdx.y;
    if (b >= nact[t]) return;
    int tid = threadIdx.x;
    if (blockIdx.x < 8) {
        int e = blockIdx.x * 256 + tid;
        const u16* src = A_bf + (long)b * P_ * E_ + e;
        const float* al = alpha + b * P_;
        float s = 0.f;
        for (int p = 0; p < P_; ++p) s = fmaf(al[p], bf2f(src[(long)p * E_]), s);
        x_bf[(long)b * XK_ + EMB_ + e] = f2bf(s * fbuf[(long)b * E_ + e]);
    } else {
        int tok = caps_s[b * L_ + t];
        for (int k = tid; k < EMB_; k += 256)
            x_bf[(long)b * XK_ + k] = f2bf(E_emb[(long)tok * EMB_ + k]);
    }
}

// ---------------- fused gates GEMM + LSTM pointwise ----------------
// Each wave computes 16 n-cols across all 4 gate quadrants, then applies LSTM.
// Reads h_old (bf16), writes h_new (bf16) + cbuf (f32, in place).
__global__ void __launch_bounds__(256) k_gates_lstm(
    const u16* __restrict__ x_bf, const u16* __restrict__ h_old,
    const u16* __restrict__ WT_ih, const float* __restrict__ b_ih,
    const u16* __restrict__ WT_hh, const float* __restrict__ b_hh,
    float* __restrict__ cbuf, u16* __restrict__ h_new,
    const int* __restrict__ nact, int t)
{
    int Bact = nact[t];
    if (Bact <= 0) return;
    int mmax = (Bact + 15) >> 4;
    int w = threadIdx.x >> 6, lane = threadIdx.x & 63;
    int lr = lane & 15, lk = (lane >> 4) * 8;
    int n = blockIdx.x * 64 + w * 16 + lr;
    int nc = n < D_ ? n : D_ - 1;

    f32x4 acc[4][4];   // [quadrant][mtile]
#pragma unroll
    for (int q = 0; q < 4; ++q)
#pragma unroll
        for (int m = 0; m < 4; ++m) acc[q][m] = (f32x4){0.f, 0.f, 0.f, 0.f};

    // x part: K = 2560
    {
        const u16* ap = x_bf + (long)lr * XK_ + lk;
        const u16* wp = WT_ih + (long)nc * XK_ + lk;
        for (int k = 0; k < XK_; k += 32) {
            bf16x8 aw[4];
#pragma unroll
            for (int m = 0; m < 4; ++m)
                if (m < mmax) aw[m] = *(const bf16x8*)(ap + (long)m * 16 * XK_ + k);
#pragma unroll
            for (int q = 0; q < 4; ++q) {
                bf16x8 bw = *(const bf16x8*)(wp + (long)q * D_ * XK_ + k);
#pragma unroll
                for (int m = 0; m < 4; ++m)
                    if (m < mmax) acc[q][m] = __builtin_amdgcn_mfma_f32_16x16x32_bf16(aw[m], bw, acc[q][m], 0, 0, 0);
            }
        }
    }
    // h part: K = 1024
    {
        const u16* ap = h_old + (long)lr * 1024 + lk;
        const u16* wp = WT_hh + (long)nc * 1024 + lk;
        for (int k = 0; k < 1024; k += 32) {
            bf16x8 aw[4];
#pragma unroll
            for (int m = 0; m < 4; ++m)
                if (m < mmax) aw[m] = *(const bf16x8*)(ap + (long)m * 16 * 1024 + k);
#pragma unroll
            for (int q = 0; q < 4; ++q) {
                bf16x8 bw = *(const bf16x8*)(wp + (long)q * D_ * 1024 + k);
#pragma unroll
                for (int m = 0; m < 4; ++m)
                    if (m < mmax) acc[q][m] = __builtin_amdgcn_mfma_f32_16x16x32_bf16(aw[m], bw, acc[q][m], 0, 0, 0);
            }
        }
    }
    if (n >= D_) return;
    float bi = b_ih[n] + b_hh[n];
    float bfg = b_ih[D_ + n] + b_hh[D_ + n];
    float bg = b_ih[2 * D_ + n] + b_hh[2 * D_ + n];
    float bo = b_ih[3 * D_ + n] + b_hh[3 * D_ + n];
#pragma unroll
    for (int m = 0; m < 4; ++m) {
        if (m < mmax) {
#pragma unroll
            for (int j = 0; j < 4; ++j) {
                int b = m * 16 + (lane >> 4) * 4 + j;
                if (b < Bact) {
                    float gi = acc[0][m][j] + bi;
                    float gf = acc[1][m][j] + bfg;
                    float gg = acc[2][m][j] + bg;
                    float go = acc[3][m][j] + bo;
                    float c = cbuf[(long)b * 1024 + n];
                    float cn = sigf(gf) * c + sigf(gi) * tanhf_fast(gg);
                    float hn = sigf(go) * tanhf_fast(cn);
                    cbuf[(long)b * 1024 + n] = cn;
                    h_new[(long)b * 1024 + n] = f2bf(hn);
                }
            }
        }
    }
}

extern "C" void kernel_launch(void* const* d_in, const int* in_sizes, int n_in,
                              void* d_out, int out_size, void* d_ws, size_t ws_size,
                              hipStream_t stream)
{
    const float* enc    = (const float*)d_in[0];
    const int*   caps   = (const int*)d_in[1];
    const int*   clen   = (const int*)d_in[2];
    const float* arts   = (const float*)d_in[3];
    const float* E_emb  = (const float*)d_in[6];
    const float* W_par  = (const float*)d_in[7];
    const float* b_par  = (const float*)d_in[8];
    const float* W_enc  = (const float*)d_in[9];
    const float* b_enc  = (const float*)d_in[10];
    const float* W_dec  = (const float*)d_in[11];
    const float* b_dec  = (const float*)d_in[12];
    const float* W_full = (const float*)d_in[13];
    const float* b_full = (const float*)d_in[14];
    const float* W_h    = (const float*)d_in[15];
    const float* b_h    = (const float*)d_in[16];
    const float* W_c    = (const float*)d_in[17];
    const float* b_c    = (const float*)d_in[18];
    const float* W_fb   = (const float*)d_in[19];
    const float* b_fb   = (const float*)d_in[20];
    const float* W_ih   = (const float*)d_in[21];
    const float* b_ih   = (const float*)d_in[22];
    const float* W_hh   = (const float*)d_in[23];
    const float* b_hh   = (const float*)d_in[24];
    const float* W_fc   = (const float*)d_in[25];
    const float* b_fc   = (const float*)d_in[26];

    float* out = (float*)d_out;
    float* out_preds  = out;
    float* out_caps   = out + (long)B_ * T_ * V_;
    float* out_dlens  = out_caps + B_ * L_;
    float* out_alphas = out_dlens + B_;
    float* out_sind   = out_alphas + (long)B_ * T_ * P_;

    // workspace layout (float units, 64-aligned)
    float* ws = (float*)d_ws;
    long o = 0;
    auto alloc = [&](long n) { long r = o; o += (n + 63) & ~63L; return r; };
    long o_ints   = alloc(2176);                 // sort_ind[64], dlens[64], nact[32], caps_s[1920]
    long o_decin  = alloc((long)B_ * XK_ / 2);   // bf16 [64][2560]
    long o_hbf    = alloc((long)2 * B_ * 1024 / 2); // double-buffered bf16 h
    long o_xbf    = alloc((long)B_ * XK_ / 2);
    long o_c      = alloc((long)B_ * 1024);
    long o_att2   = alloc((long)B_ * 1024);
    long o_fbuf   = alloc((long)B_ * E_);
    long o_alpha  = alloc((long)B_ * P_);
    long o_Abf    = alloc((long)12544 * E_ / 2);
    long o_att1   = alloc((long)12544 * 1024 / 2);
    long o_wtenc  = alloc((long)1024 * 2048 / 2);
    long o_wtdec  = alloc((long)1024 * 1024 / 2);
    long o_wtfb   = alloc((long)2048 * 1024 / 2);
    long o_wtih   = alloc((long)4096 * 2560 / 2);
    long o_wthh   = alloc((long)4096 * 1024 / 2);
    long o_wtfc   = alloc((long)10048 * 1024 / 2);

    int* sort_ind = (int*)(ws + o_ints);
    int* dlens_i  = sort_ind + 64;
    int* nact     = dlens_i + 64;
    int* caps_s   = nact + 32;
    u16*   dec_in = (u16*)(ws + o_decin);
    u16*   h_bf   = (u16*)(ws + o_hbf);        // 2 buffers of [64][1024]
    u16*   x_bf   = (u16*)(ws + o_xbf);
    float* cbuf   = ws + o_c;
    float* att2   = ws + o_att2;
    float* fbuf   = ws + o_fbuf;
    float* alpha  = ws + o_alpha;
    u16*   A_bf   = (u16*)(ws + o_Abf);
    u16*   att1   = (u16*)(ws + o_att1);
    u16*   WT_enc = (u16*)(ws + o_wtenc);
    u16*   WT_dec = (u16*)(ws + o_wtdec);
    u16*   WT_fb  = (u16*)(ws + o_wtfb);
    u16*   WT_ih  = (u16*)(ws + o_wtih);
    u16*   WT_hh  = (u16*)(ws + o_wthh);
    u16*   WT_fc  = (u16*)(ws + o_wtfc);
    // transient: WT_h / WT_c live in att1's region (overwritten later by k_att1_mfma)
    u16*   WT_h   = att1;
    u16*   WT_c   = att1 + (long)1024 * XK_;

    long n4 = ((long)B_ * T_ * V_ + B_ * L_ + B_ + (long)B_ * T_ * P_ + B_) / 4;
    k_zero<<<dim3((unsigned)((n4 + 255) / 256)), 256, 0, stream>>>((float4*)d_out, n4);
    k_setup<<<1, 64, 0, stream>>>(clen, caps, out_caps, out_dlens, out_sind,
                                  sort_ind, dlens_i, nact, caps_s);

    // build dec_in (bf16 [64][2560]): mean || context || pad
    k_encmean<<<dim3(8, 64), 256, 0, stream>>>(enc, sort_ind, dec_in);
    k_ctx<<<dim3(2, 64), 256, 0, stream>>>(arts, W_par, b_par, sort_ind, dec_in);

    dim3 tb(32, 8);
    // transient transposes for h0/c0 into att1 region
    k_transpose<<<dim3(1024/32, 2560/32), tb, 0, stream>>>(W_h, WT_h, 2548, 1012, 2560, 1024);
    k_transpose<<<dim3(1024/32, 2560/32), tb, 0, stream>>>(W_c, WT_c, 2548, 1012, 2560, 1024);
    // h0 (bf16, pad-zero cols) and c0 (f32)
    k_skinny<0,1,1><<<dim3(16), 256, 0, stream>>>(dec_in, WT_h, XK_, b_h, h_bf, 1024L, 0L, D_,
                                                  nact, -1);
    k_skinny<0,0,1><<<dim3(16), 256, 0, stream>>>(dec_in, WT_c, XK_, b_c, cbuf, 1024L, 0L, D_,
                                                  nact, -1);

    // persistent weight transposes
    k_transpose<<<dim3(1024/32, 2048/32), tb, 0, stream>>>(W_enc, WT_enc, 2048, 1012, 2048, 1024);
    k_transpose<<<dim3(1024/32, 1024/32), tb, 0, stream>>>(W_dec, WT_dec, 1012, 1012, 1024, 1024);
    k_transpose<<<dim3(2048/32, 1024/32), tb, 0, stream>>>(W_fb, WT_fb, 1012, 2048, 1024, 2048);
    k_transpose<<<dim3(4096/32, 2560/32), tb, 0, stream>>>(W_ih, WT_ih, 2560, 4048, 2560, 4096);
    k_transpose<<<dim3(4096/32, 1024/32), tb, 0, stream>>>(W_hh, WT_hh, 1012, 4048, 1024, 4096);
    k_transpose<<<dim3(10048/32, 1024/32), tb, 0, stream>>>(W_fc, WT_fc, 1012, 10000, 1024, 10048);

    k_cvt_enc<<<dim3(2, 12544), 256, 0, stream>>>(enc, sort_ind, A_bf);
    // overwrites WT_h/WT_c region (h0/c0 already computed; stream order guarantees)
    k_att1_mfma<<<dim3(4, 196), 256, 0, stream>>>(A_bf, WT_enc, b_enc, att1);

    for (int t = 0; t < T_; ++t) {
        const u16* h_old = h_bf + (long)(t & 1) * B_ * 1024;
        u16* h_new = h_bf + (long)((t + 1) & 1) * B_ * 1024;
        k_att2fb<<<dim3(48), 256, 0, stream>>>(h_old, WT_dec, WT_fb, b_dec, b_fb,
                                               att2, fbuf, nact, t);
        k_attn<<<dim3(64), 256, 0, stream>>>(att1, att2, W_full, b_full,
                                             alpha, out_alphas, nact, t);
        k_awe_x<<<dim3(9, 64), 256, 0, stream>>>(A_bf, alpha, fbuf, E_emb, caps_s, x_bf, nact, t);
        k_gates_lstm<<<dim3(16), 256, 0, stream>>>(x_bf, h_old, WT_ih, b_ih, WT_hh, b_hh,
                                                   cbuf, h_new, nact, t);
        k_skinny<0,0,0><<<dim3(157), 256, 0, stream>>>(h_new, WT_fc, 1024, b_fc, out_preds,
                                                       (long)T_ * V_, (long)t * V_, V_, nact, t);
    }
}

// Round 4
// 4592.308 us; speedup vs baseline: 1.7250x; 1.7250x over previous
//
#include <hip/hip_runtime.h>
#include <math.h>

// Problem constants
#define B_   64
#define P_   196      // 14*14 pixels
#define E_   2048
#define L_   30
#define T_   29       // L-1 decode steps
#define V_   10000
#define EMB_ 512
#define AML_ 768
#define ADL_ 500
#define D_   1012     // 512+ADL
#define A_   1012
#define G4_  4048     // 4*D
#define XK_  2560     // EMB+E

typedef unsigned short u16;
typedef __attribute__((ext_vector_type(8))) short bf16x8;
typedef __attribute__((ext_vector_type(4))) float f32x4;

__device__ __forceinline__ float sigf(float x) { return 1.f / (1.f + __expf(-x)); }
__device__ __forceinline__ float tanhf_fast(float x) { return 1.f - 2.f / (__expf(2.f * x) + 1.f); }
__device__ __forceinline__ u16 f2bf(float f) {
    unsigned u = __float_as_uint(f);
    return (u16)((u + 0x7FFFu + ((u >> 16) & 1u)) >> 16);
}
__device__ __forceinline__ float bf2f(u16 v) { return __uint_as_float(((unsigned)v) << 16); }

// ---------------- setup ----------------
__global__ void k_setup(const int* __restrict__ clen, const int* __restrict__ caps,
                        float* __restrict__ out_caps, float* __restrict__ out_dlens,
                        float* __restrict__ out_sind,
                        int* __restrict__ sort_ind, int* __restrict__ dlens_i,
                        int* __restrict__ nact, int* __restrict__ caps_s)
{
    __shared__ int lens[B_];
    int t = threadIdx.x;
    if (t < B_) lens[t] = clen[t];
    __syncthreads();
    if (t < B_) {
        int my = lens[t];
        int rank = 0;
        for (int j = 0; j < B_; ++j) {
            int lj = lens[j];
            if (lj > my || (lj == my && j < t)) rank++;  // stable descending
        }
        sort_ind[rank] = t;
    }
    __syncthreads();
    if (t < B_) {
        int orig = sort_ind[t];
        int dl = lens[orig] - 1;
        dlens_i[t] = dl;
        out_dlens[t] = (float)dl;
        out_sind[t] = (float)orig;
        for (int j = 0; j < L_; ++j) {
            int cv = caps[orig * L_ + j];
            caps_s[t * L_ + j] = cv;
            out_caps[t * L_ + j] = (float)cv;
        }
    }
    __syncthreads();
    if (t < T_) {
        int cnt = 0;
        for (int j = 0; j < B_; ++j) cnt += (dlens_i[j] > t) ? 1 : 0;
        nact[t] = cnt;
    }
}

// ---------------- zero entire output buffer ----------------
__global__ void k_zero(float4* __restrict__ p, long n4)
{
    long i = (long)blockIdx.x * 256 + threadIdx.x;
    if (i < n4) p[i] = make_float4(0.f, 0.f, 0.f, 0.f);
}

// ---------------- gather + fp32->bf16 convert enc rows into sorted order ----------------
__global__ void k_cvt_enc(const float* __restrict__ enc, const int* __restrict__ sort_ind,
                          u16* __restrict__ A_bf)
{
    int row = blockIdx.y;                 // 0..12543  (b*196+p sorted)
    int b = row / 196, p = row - b * 196;
    int e4 = (blockIdx.x * 256 + threadIdx.x) * 4;   // 0..2044
    const float* src = enc + ((long)sort_ind[b] * 196 + p) * E_ + e4;
    float4 v = *(const float4*)src;
    unsigned lo = (unsigned)f2bf(v.x) | ((unsigned)f2bf(v.y) << 16);
    unsigned hi = (unsigned)f2bf(v.z) | ((unsigned)f2bf(v.w) << 16);
    uint2 pk; pk.x = lo; pk.y = hi;
    *(uint2*)(A_bf + (long)row * E_ + e4) = pk;
}

// ---------------- tiled transpose + convert: fp32 [K][N] -> bf16 [Np][Kp] (pads=0) ----
__global__ void k_transpose(const float* __restrict__ src, u16* __restrict__ dst,
                            int K, int N, int Kp, int Np)
{
    __shared__ float tile[32][33];
    int n0 = blockIdx.x * 32, k0 = blockIdx.y * 32;
    int tx = threadIdx.x, ty = threadIdx.y;   // (32,8)
    for (int r = ty; r < 32; r += 8) {
        int k = k0 + r, n = n0 + tx;
        tile[r][tx] = (k < K && n < N) ? src[(long)k * N + n] : 0.f;
    }
    __syncthreads();
    for (int r = ty; r < 32; r += 8) {
        int n = n0 + r, k = k0 + tx;
        if (n < Np && k < Kp) dst[(long)n * Kp + k] = f2bf(tile[tx][r]);
    }
}

// ---------------- enc mean -> dec_in_bf cols [0,2048) ----------------
__global__ void k_encmean(const float* __restrict__ enc, const int* __restrict__ sort_ind,
                          u16* __restrict__ dec_in)
{
    int b = blockIdx.y;
    int e = blockIdx.x * 256 + threadIdx.x;   // < 2048
    int orig = sort_ind[b];
    const float* src = enc + (long)orig * P_ * E_ + e;
    float s = 0.f;
    for (int p = 0; p < P_; ++p) s += src[(long)p * E_];
    dec_in[(long)b * XK_ + e] = f2bf(s * (1.f / 196.f));
}

// ---------------- context -> dec_in_bf cols [2048,2560), pad 0 ----------------
__global__ void k_ctx(const float* __restrict__ arts, const float* __restrict__ W_par,
                      const float* __restrict__ b_par, const int* __restrict__ sort_ind,
                      u16* __restrict__ dec_in)
{
    int b = blockIdx.y;
    int k = blockIdx.x * 256 + threadIdx.x;   // < 512
    if (k >= 512) return;
    float s = 0.f;
    if (k < ADL_) {
        int orig = sort_ind[b];
        const float* ar = arts + (long)orig * AML_;
        s = b_par[k];
        for (int m = 0; m < AML_; ++m) s = fmaf(ar[m], W_par[m * ADL_ + k], s);
    }
    dec_in[(long)b * XK_ + E_ + k] = f2bf(s);
}

// ---------------- att1 MFMA ----------------
__global__ void __launch_bounds__(256) k_att1_mfma(
    const u16* __restrict__ A, const u16* __restrict__ W,
    const float* __restrict__ bias, u16* __restrict__ Yb)
{
    int w = threadIdx.x >> 6, lane = threadIdx.x & 63;
    int lr = lane & 15, lk = (lane >> 4) * 8;
    int n0 = blockIdx.x * 256 + w * 64;
    int r0 = blockIdx.y * 64;
    f32x4 acc[4][4];
#pragma unroll
    for (int i = 0; i < 4; ++i)
#pragma unroll
        for (int j = 0; j < 4; ++j) acc[i][j] = (f32x4){0.f, 0.f, 0.f, 0.f};
    const u16* ap = A + (long)(r0 + lr) * E_ + lk;
    const u16* wp = W + (long)(n0 + lr) * E_ + lk;
    for (int k = 0; k < E_; k += 32) {
        bf16x8 af[4], bf[4];
#pragma unroll
        for (int mt = 0; mt < 4; ++mt) af[mt] = *(const bf16x8*)(ap + (long)mt * 16 * E_ + k);
#pragma unroll
        for (int nt = 0; nt < 4; ++nt) bf[nt] = *(const bf16x8*)(wp + (long)nt * 16 * E_ + k);
#pragma unroll
        for (int mt = 0; mt < 4; ++mt)
#pragma unroll
            for (int nt = 0; nt < 4; ++nt)
                acc[mt][nt] = __builtin_amdgcn_mfma_f32_16x16x32_bf16(af[mt], bf[nt], acc[mt][nt], 0, 0, 0);
    }
#pragma unroll
    for (int mt = 0; mt < 4; ++mt) {
#pragma unroll
        for (int nt = 0; nt < 4; ++nt) {
            int n = n0 + nt * 16 + lr;
            float bv = (n < A_) ? bias[n] : 0.f;
#pragma unroll
            for (int j = 0; j < 4; ++j) {
                int row = r0 + mt * 16 + (lane >> 4) * 4 + j;
                u16 outv = (n < A_) ? f2bf(acc[mt][nt][j] + bv) : (u16)0;
                Yb[(long)row * 1024 + n] = outv;
            }
        }
    }
}

// ---------------- skinny MFMA (h0/c0 + fc) ----------------
template <int ACT, int OUT, int PADZ>
__global__ void __launch_bounds__(256) k_skinny(
    const u16* __restrict__ A1, const u16* __restrict__ W1, int K1,
    const float* __restrict__ bias1, void* __restrict__ Yv,
    long ldY, long offY, int Nmax,
    const int* __restrict__ nact, int t)
{
    int Bact = (t >= 0) ? nact[t] : B_;
    if (Bact <= 0) return;
    int mmax = (Bact + 15) >> 4;
    int w = threadIdx.x >> 6, lane = threadIdx.x & 63;
    int lr = lane & 15, lk = (lane >> 4) * 8;
    int n0 = blockIdx.x * 64 + w * 16;
    f32x4 acc[4];
#pragma unroll
    for (int m = 0; m < 4; ++m) acc[m] = (f32x4){0.f, 0.f, 0.f, 0.f};

    int n = n0 + lr;
    int nc = n < Nmax ? n : Nmax - 1;
    const u16* a1p = A1 + (long)lr * K1 + lk;
    const u16* w1p = W1 + (long)nc * K1 + lk;
    for (int k = 0; k < K1; k += 32) {
        bf16x8 bw = *(const bf16x8*)(w1p + k);
#pragma unroll
        for (int m = 0; m < 4; ++m)
            if (m < mmax) {
                bf16x8 aw = *(const bf16x8*)(a1p + (long)m * 16 * K1 + k);
                acc[m] = __builtin_amdgcn_mfma_f32_16x16x32_bf16(aw, bw, acc[m], 0, 0, 0);
            }
    }
    float bv = (n < Nmax) ? bias1[n] : 0.f;
#pragma unroll
    for (int m = 0; m < 4; ++m) {
        if (m < mmax) {
#pragma unroll
            for (int j = 0; j < 4; ++j) {
                int b = m * 16 + (lane >> 4) * 4 + j;
                if (b < Bact) {
                    float v = acc[m][j] + bv;
                    if (ACT == 1) v = sigf(v);
                    if (n < Nmax) {
                        if (OUT == 1) ((u16*)Yv)[(long)b * ldY + offY + n] = f2bf(v);
                        else          ((float*)Yv)[(long)b * ldY + offY + n] = v;
                    } else if (PADZ) {
                        if (OUT == 1) ((u16*)Yv)[(long)b * ldY + offY + n] = 0;
                        else          ((float*)Yv)[(long)b * ldY + offY + n] = 0.f;
                    }
                }
            }
        }
    }
}

// ---------------- att2+fb, K-split x2 into partial buffers ----------------
// grid 96: kh = blockIdx.x/48; nb = blockIdx.x%48; nb<16 -> att2 stripe, else fb stripe.
// att2p: [2][64][1024] f32 (no activation), fbp: [2][64][2048] f32 (no sigmoid yet)
__global__ void __launch_bounds__(256) k_att2fb(
    const u16* __restrict__ h_bf, const u16* __restrict__ WT_dec,
    const u16* __restrict__ WT_fb, const float* __restrict__ b_dec,
    const float* __restrict__ b_fb, float* __restrict__ att2p,
    float* __restrict__ fbp, const int* __restrict__ nact, int t)
{
    int Bact = nact[t];
    if (Bact <= 0) return;
    int mmax = (Bact + 15) >> 4;
    int kh = blockIdx.x >= 48;
    int nb = blockIdx.x - (kh ? 48 : 0);
    int isfb = nb >= 16;
    const u16* W = isfb ? WT_fb : WT_dec;
    const float* bias = isfb ? b_fb : b_dec;
    int Nmax = isfb ? E_ : A_;
    int nb2 = isfb ? nb - 16 : nb;
    long ldY = isfb ? (long)E_ : 1024L;
    float* Y = (isfb ? fbp : att2p) + (long)kh * B_ * ldY;

    int w = threadIdx.x >> 6, lane = threadIdx.x & 63;
    int lr = lane & 15, lk = (lane >> 4) * 8;
    int n = nb2 * 64 + w * 16 + lr;
    int nc = n < Nmax ? n : Nmax - 1;
    int k0 = kh * 512;
    f32x4 acc[4];
#pragma unroll
    for (int m = 0; m < 4; ++m) acc[m] = (f32x4){0.f, 0.f, 0.f, 0.f};
    const u16* ap = h_bf + (long)lr * 1024 + k0 + lk;
    const u16* wp = W + (long)nc * 1024 + k0 + lk;
    for (int k = 0; k < 512; k += 32) {
        bf16x8 bw = *(const bf16x8*)(wp + k);
#pragma unroll
        for (int m = 0; m < 4; ++m)
            if (m < mmax) {
                bf16x8 aw = *(const bf16x8*)(ap + (long)m * 16 * 1024 + k);
                acc[m] = __builtin_amdgcn_mfma_f32_16x16x32_bf16(aw, bw, acc[m], 0, 0, 0);
            }
    }
    if (n >= Nmax) return;
    float bv = (kh == 0) ? bias[n] : 0.f;
#pragma unroll
    for (int m = 0; m < 4; ++m) {
        if (m < mmax) {
#pragma unroll
            for (int j = 0; j < 4; ++j) {
                int b = m * 16 + (lane >> 4) * 4 + j;
                if (b < Bact) Y[(long)b * ldY + n] = acc[m][j] + bv;
            }
        }
    }
}

// ---------------- scores: relu(att1_bf + att2p0 + att2p1) @ W_full + b_full ----------------
__global__ void k_scores(const u16* __restrict__ att1, const float* __restrict__ att2p,
                         const float* __restrict__ W_full, const float* __restrict__ b_full,
                         float* __restrict__ scores, const int* __restrict__ nact, int t)
{
    int b = blockIdx.y;
    if (b >= nact[t]) return;
    int wv = threadIdx.x >> 6;
    int lane = threadIdx.x & 63;
    int p = blockIdx.x * 4 + wv;   // 49*4 = 196
    const u16* a1 = att1 + ((long)b * P_ + p) * 1024;
    const float* a20 = att2p + (long)b * 1024;
    const float* a21 = att2p + (long)B_ * 1024 + (long)b * 1024;
    float acc = 0.f;
    for (int j2 = lane; j2 < 506; j2 += 64) {
        unsigned pk = *(const unsigned*)(a1 + 2 * j2);
        float2 p0 = *(const float2*)(a20 + 2 * j2);
        float2 p1 = *(const float2*)(a21 + 2 * j2);
        float2 wv2 = *(const float2*)(W_full + 2 * j2);
        float v0 = bf2f((u16)(pk & 0xFFFF)) + p0.x + p1.x;
        float v1 = bf2f((u16)(pk >> 16)) + p0.y + p1.y;
        v0 = v0 > 0.f ? v0 : 0.f;
        v1 = v1 > 0.f ? v1 : 0.f;
        acc = fmaf(v0, wv2.x, acc);
        acc = fmaf(v1, wv2.y, acc);
    }
    for (int m = 32; m >= 1; m >>= 1) acc += __shfl_xor(acc, m);
    if (lane == 0) scores[b * P_ + p] = acc + b_full[0];
}

// ---------------- awe + local softmax + emb gather + alphas write ----------------
// grid (9, 64). Each block computes softmax(scores[b]) in LDS, then:
// blocks 0-7: weighted enc sum * sigmoid(fb partial sum) -> x_bf awe part
// block 8: emb gather -> x_bf emb part; writes alphas_out
__global__ void __launch_bounds__(256) k_awe_x(
    const u16* __restrict__ A_bf, const float* __restrict__ scores,
    const float* __restrict__ fbp, const float* __restrict__ E_emb,
    const int* __restrict__ caps_s, u16* __restrict__ x_bf,
    float* __restrict__ alphas_out, const int* __restrict__ nact, int t)
{
    int b = blockIdx.y;
    if (b >= nact[t]) return;
    int tid = threadIdx.x;
    int w = tid >> 6, lane = tid & 63;
    __shared__ float al[P_];
    __shared__ float red[4];
    float v = (tid < P_) ? scores[b * P_ + tid] : -1e30f;
    float m = v;
    for (int s = 32; s >= 1; s >>= 1) m = fmaxf(m, __shfl_xor(m, s));
    if (lane == 0) red[w] = m;
    __syncthreads();
    m = fmaxf(fmaxf(red[0], red[1]), fmaxf(red[2], red[3]));
    float e = (tid < P_) ? __expf(v - m) : 0.f;
    float s_ = e;
    for (int s = 32; s >= 1; s >>= 1) s_ += __shfl_xor(s_, s);
    __syncthreads();
    if (lane == 0) red[w] = s_;
    __syncthreads();
    s_ = red[0] + red[1] + red[2] + red[3];
    if (tid < P_) al[tid] = e / s_;
    __syncthreads();

    if (blockIdx.x < 8) {
        int e0 = blockIdx.x * 256 + tid;
        const u16* src = A_bf + (long)b * P_ * E_ + e0;
        float s0 = 0.f, s1 = 0.f, s2 = 0.f, s3 = 0.f;
        for (int p = 0; p < P_; p += 4) {
            s0 = fmaf(al[p],     bf2f(src[(long)p * E_]), s0);
            s1 = fmaf(al[p + 1], bf2f(src[(long)(p + 1) * E_]), s1);
            s2 = fmaf(al[p + 2], bf2f(src[(long)(p + 2) * E_]), s2);
            s3 = fmaf(al[p + 3], bf2f(src[(long)(p + 3) * E_]), s3);
        }
        float g = sigf(fbp[(long)b * E_ + e0] + fbp[(long)(B_ + b) * E_ + e0]);
        x_bf[(long)b * XK_ + EMB_ + e0] = f2bf((s0 + s1 + s2 + s3) * g);
    } else {
        int tok = caps_s[b * L_ + t];
        for (int k = tid; k < EMB_; k += 256)
            x_bf[(long)b * XK_ + k] = f2bf(E_emb[(long)tok * EMB_ + k]);
        if (tid < P_) alphas_out[((long)b * T_ + t) * P_ + tid] = al[tid];
    }
}

// ---------------- fused gates GEMM + LSTM, 64 blocks, wave = gate quadrant ----------------
__global__ void __launch_bounds__(256) k_gates_lstm(
    const u16* __restrict__ x_bf, const u16* __restrict__ h_old,
    const u16* __restrict__ WT_ih, const float* __restrict__ b_ih,
    const u16* __restrict__ WT_hh, const float* __restrict__ b_hh,
    float* __restrict__ cbuf, u16* __restrict__ h_new,
    const int* __restrict__ nact, int t)
{
    int Bact = nact[t];
    if (Bact <= 0) return;
    int mmax = (Bact + 15) >> 4;
    int q = threadIdx.x >> 6;                 // wave = quadrant (i,f,g,o)
    int lane = threadIdx.x & 63;
    int lr = lane & 15, lk = (lane >> 4) * 8;
    int n = blockIdx.x * 16 + lr;             // 64 blocks x 16 cols
    int nc = n < D_ ? n : D_ - 1;

    f32x4 acc[4];
#pragma unroll
    for (int m = 0; m < 4; ++m) acc[m] = (f32x4){0.f, 0.f, 0.f, 0.f};
    {
        const u16* ap = x_bf + (long)lr * XK_ + lk;
        const u16* wp = WT_ih + ((long)q * D_ + nc) * XK_ + lk;
        for (int k = 0; k < XK_; k += 32) {
            bf16x8 bw = *(const bf16x8*)(wp + k);
#pragma unroll
            for (int m = 0; m < 4; ++m)
                if (m < mmax) {
                    bf16x8 aw = *(const bf16x8*)(ap + (long)m * 16 * XK_ + k);
                    acc[m] = __builtin_amdgcn_mfma_f32_16x16x32_bf16(aw, bw, acc[m], 0, 0, 0);
                }
        }
    }
    {
        const u16* ap = h_old + (long)lr * 1024 + lk;
        const u16* wp = WT_hh + ((long)q * D_ + nc) * 1024 + lk;
        for (int k = 0; k < 1024; k += 32) {
            bf16x8 bw = *(const bf16x8*)(wp + k);
#pragma unroll
            for (int m = 0; m < 4; ++m)
                if (m < mmax) {
                    bf16x8 aw = *(const bf16x8*)(ap + (long)m * 16 * 1024 + k);
                    acc[m] = __builtin_amdgcn_mfma_f32_16x16x32_bf16(aw, bw, acc[m], 0, 0, 0);
                }
        }
    }
    __shared__ float g_lds[4][64][17];
#pragma unroll
    for (int m = 0; m < 4; ++m) {
        if (m < mmax) {
#pragma unroll
            for (int j = 0; j < 4; ++j) {
                int bb = m * 16 + (lane >> 4) * 4 + j;
                g_lds[q][bb][lr] = acc[m][j];
            }
        }
    }
    __syncthreads();
#pragma unroll
    for (int i = 0; i < 4; ++i) {
        int idx = threadIdx.x + i * 256;      // 1024 (b,col) pairs
        int bb = idx >> 4, col = idx & 15;
        int n2 = blockIdx.x * 16 + col;
        if (n2 >= D_) {
            if (n2 < 1024) h_new[(long)bb * 1024 + n2] = 0;
            continue;
        }
        if (bb >= Bact) continue;
        float gi = g_lds[0][bb][col] + b_ih[n2] + b_hh[n2];
        float gf = g_lds[1][bb][col] + b_ih[D_ + n2] + b_hh[D_ + n2];
        float gg = g_lds[2][bb][col] + b_ih[2 * D_ + n2] + b_hh[2 * D_ + n2];
        float go = g_lds[3][bb][col] + b_ih[3 * D_ + n2] + b_hh[3 * D_ + n2];
        float c = cbuf[(long)bb * 1024 + n2];
        float cn = sigf(gf) * c + sigf(gi) * tanhf_fast(gg);
        float hn = sigf(go) * tanhf_fast(cn);
        cbuf[(long)bb * 1024 + n2] = cn;
        h_new[(long)bb * 1024 + n2] = f2bf(hn);
    }
}

extern "C" void kernel_launch(void* const* d_in, const int* in_sizes, int n_in,
                              void* d_out, int out_size, void* d_ws, size_t ws_size,
                              hipStream_t stream)
{
    const float* enc    = (const float*)d_in[0];
    const int*   caps   = (const int*)d_in[1];
    const int*   clen   = (const int*)d_in[2];
    const float* arts   = (const float*)d_in[3];
    const float* E_emb  = (const float*)d_in[6];
    const float* W_par  = (const float*)d_in[7];
    const float* b_par  = (const float*)d_in[8];
    const float* W_enc  = (const float*)d_in[9];
    const float* b_enc  = (const float*)d_in[10];
    const float* W_dec  = (const float*)d_in[11];
    const float* b_dec  = (const float*)d_in[12];
    const float* W_full = (const float*)d_in[13];
    const float* b_full = (const float*)d_in[14];
    const float* W_h    = (const float*)d_in[15];
    const float* b_h    = (const float*)d_in[16];
    const float* W_c    = (const float*)d_in[17];
    const float* b_c    = (const float*)d_in[18];
    const float* W_fb   = (const float*)d_in[19];
    const float* b_fb   = (const float*)d_in[20];
    const float* W_ih   = (const float*)d_in[21];
    const float* b_ih   = (const float*)d_in[22];
    const float* W_hh   = (const float*)d_in[23];
    const float* b_hh   = (const float*)d_in[24];
    const float* W_fc   = (const float*)d_in[25];
    const float* b_fc   = (const float*)d_in[26];

    float* out = (float*)d_out;
    float* out_preds  = out;
    float* out_caps   = out + (long)B_ * T_ * V_;
    float* out_dlens  = out_caps + B_ * L_;
    float* out_alphas = out_dlens + B_;
    float* out_sind   = out_alphas + (long)B_ * T_ * P_;

    // workspace layout (float units, 64-aligned)
    float* ws = (float*)d_ws;
    long o = 0;
    auto alloc = [&](long n) { long r = o; o += (n + 63) & ~63L; return r; };
    long o_ints   = alloc(2176);
    long o_decin  = alloc((long)B_ * XK_ / 2);
    long o_hbf    = alloc((long)2 * B_ * 1024 / 2);
    long o_xbf    = alloc((long)B_ * XK_ / 2);
    long o_c      = alloc((long)B_ * 1024);
    long o_att2p  = alloc((long)2 * B_ * 1024);
    long o_fbp    = alloc((long)2 * B_ * E_);
    long o_scores = alloc((long)B_ * P_);
    long o_Abf    = alloc((long)12544 * E_ / 2);
    long o_att1   = alloc((long)12544 * 1024 / 2);
    long o_wtenc  = alloc((long)1024 * 2048 / 2);
    long o_wtdec  = alloc((long)1024 * 1024 / 2);
    long o_wtfb   = alloc((long)2048 * 1024 / 2);
    long o_wtih   = alloc((long)4096 * 2560 / 2);
    long o_wthh   = alloc((long)4096 * 1024 / 2);
    long o_wtfc   = alloc((long)10048 * 1024 / 2);

    int* sort_ind = (int*)(ws + o_ints);
    int* dlens_i  = sort_ind + 64;
    int* nact     = dlens_i + 64;
    int* caps_s   = nact + 32;
    u16*   dec_in = (u16*)(ws + o_decin);
    u16*   h_bf   = (u16*)(ws + o_hbf);
    u16*   x_bf   = (u16*)(ws + o_xbf);
    float* cbuf   = ws + o_c;
    float* att2p  = ws + o_att2p;
    float* fbp    = ws + o_fbp;
    float* scores = ws + o_scores;
    u16*   A_bf   = (u16*)(ws + o_Abf);
    u16*   att1   = (u16*)(ws + o_att1);
    u16*   WT_enc = (u16*)(ws + o_wtenc);
    u16*   WT_dec = (u16*)(ws + o_wtdec);
    u16*   WT_fb  = (u16*)(ws + o_wtfb);
    u16*   WT_ih  = (u16*)(ws + o_wtih);
    u16*   WT_hh  = (u16*)(ws + o_wthh);
    u16*   WT_fc  = (u16*)(ws + o_wtfc);
    // transient: WT_h / WT_c live in att1's region (overwritten later by k_att1_mfma)
    u16*   WT_h   = att1;
    u16*   WT_c   = att1 + (long)1024 * XK_;

    long n4 = ((long)B_ * T_ * V_ + B_ * L_ + B_ + (long)B_ * T_ * P_ + B_) / 4;
    k_zero<<<dim3((unsigned)((n4 + 255) / 256)), 256, 0, stream>>>((float4*)d_out, n4);
    k_setup<<<1, 64, 0, stream>>>(clen, caps, out_caps, out_dlens, out_sind,
                                  sort_ind, dlens_i, nact, caps_s);

    k_encmean<<<dim3(8, 64), 256, 0, stream>>>(enc, sort_ind, dec_in);
    k_ctx<<<dim3(2, 64), 256, 0, stream>>>(arts, W_par, b_par, sort_ind, dec_in);

    dim3 tb(32, 8);
    k_transpose<<<dim3(1024/32, 2560/32), tb, 0, stream>>>(W_h, WT_h, 2548, 1012, 2560, 1024);
    k_transpose<<<dim3(1024/32, 2560/32), tb, 0, stream>>>(W_c, WT_c, 2548, 1012, 2560, 1024);
    k_skinny<0,1,1><<<dim3(16), 256, 0, stream>>>(dec_in, WT_h, XK_, b_h, h_bf, 1024L, 0L, D_,
                                                  nact, -1);
    k_skinny<0,0,1><<<dim3(16), 256, 0, stream>>>(dec_in, WT_c, XK_, b_c, cbuf, 1024L, 0L, D_,
                                                  nact, -1);

    k_transpose<<<dim3(1024/32, 2048/32), tb, 0, stream>>>(W_enc, WT_enc, 2048, 1012, 2048, 1024);
    k_transpose<<<dim3(1024/32, 1024/32), tb, 0, stream>>>(W_dec, WT_dec, 1012, 1012, 1024, 1024);
    k_transpose<<<dim3(2048/32, 1024/32), tb, 0, stream>>>(W_fb, WT_fb, 1012, 2048, 1024, 2048);
    k_transpose<<<dim3(4096/32, 2560/32), tb, 0, stream>>>(W_ih, WT_ih, 2560, 4048, 2560, 4096);
    k_transpose<<<dim3(4096/32, 1024/32), tb, 0, stream>>>(W_hh, WT_hh, 1012, 4048, 1024, 4096);
    k_transpose<<<dim3(10048/32, 1024/32), tb, 0, stream>>>(W_fc, WT_fc, 1012, 10000, 1024, 10048);

    k_cvt_enc<<<dim3(2, 12544), 256, 0, stream>>>(enc, sort_ind, A_bf);
    k_att1_mfma<<<dim3(4, 196), 256, 0, stream>>>(A_bf, WT_enc, b_enc, att1);

    for (int t = 0; t < T_; ++t) {
        const u16* h_old = h_bf + (long)(t & 1) * B_ * 1024;
        u16* h_new = h_bf + (long)((t + 1) & 1) * B_ * 1024;
        k_att2fb<<<dim3(96), 256, 0, stream>>>(h_old, WT_dec, WT_fb, b_dec, b_fb,
                                               att2p, fbp, nact, t);
        k_scores<<<dim3(49, 64), 256, 0, stream>>>(att1, att2p, W_full, b_full, scores, nact, t);
        k_awe_x<<<dim3(9, 64), 256, 0, stream>>>(A_bf, scores, fbp, E_emb, caps_s,
                                                 x_bf, out_alphas, nact, t);
        k_gates_lstm<<<dim3(64), 256, 0, stream>>>(x_bf, h_old, WT_ih, b_ih, WT_hh, b_hh,
                                                   cbuf, h_new, nact, t);
        k_skinny<0,0,0><<<dim3(157), 256, 0, stream>>>(h_new, WT_fc, 1024, b_fc, out_preds,
                                                       (long)T_ * V_, (long)t * V_, V_, nact, t);
    }
}

// Round 5
// 3110.576 us; speedup vs baseline: 2.5467x; 1.4764x over previous
//
#include <hip/hip_runtime.h>
#include <math.h>

// Problem constants
#define B_   64
#define P_   196      // 14*14 pixels
#define E_   2048
#define L_   30
#define T_   29       // L-1 decode steps
#define V_   10000
#define EMB_ 512
#define AML_ 768
#define ADL_ 500
#define D_   1012     // 512+ADL
#define A_   1012
#define G4_  4048     // 4*D
#define XK_  2560     // EMB+E

typedef unsigned short u16;
typedef __attribute__((ext_vector_type(8))) short bf16x8;
typedef __attribute__((ext_vector_type(4))) float f32x4;

__device__ __forceinline__ float sigf(float x) { return 1.f / (1.f + __expf(-x)); }
__device__ __forceinline__ float tanhf_fast(float x) { return 1.f - 2.f / (__expf(2.f * x) + 1.f); }
__device__ __forceinline__ u16 f2bf(float f) {
    unsigned u = __float_as_uint(f);
    return (u16)((u + 0x7FFFu + ((u >> 16) & 1u)) >> 16);
}
__device__ __forceinline__ float bf2f(u16 v) { return __uint_as_float(((unsigned)v) << 16); }

// ---------------- setup ----------------
__global__ void k_setup(const int* __restrict__ clen, const int* __restrict__ caps,
                        float* __restrict__ out_caps, float* __restrict__ out_dlens,
                        float* __restrict__ out_sind,
                        int* __restrict__ sort_ind, int* __restrict__ dlens_i,
                        int* __restrict__ nact, int* __restrict__ caps_s)
{
    __shared__ int lens[B_];
    int t = threadIdx.x;
    if (t < B_) lens[t] = clen[t];
    __syncthreads();
    if (t < B_) {
        int my = lens[t];
        int rank = 0;
        for (int j = 0; j < B_; ++j) {
            int lj = lens[j];
            if (lj > my || (lj == my && j < t)) rank++;  // stable descending
        }
        sort_ind[rank] = t;
    }
    __syncthreads();
    if (t < B_) {
        int orig = sort_ind[t];
        int dl = lens[orig] - 1;
        dlens_i[t] = dl;
        out_dlens[t] = (float)dl;
        out_sind[t] = (float)orig;
        for (int j = 0; j < L_; ++j) {
            int cv = caps[orig * L_ + j];
            caps_s[t * L_ + j] = cv;
            out_caps[t * L_ + j] = (float)cv;
        }
    }
    __syncthreads();
    if (t < T_) {
        int cnt = 0;
        for (int j = 0; j < B_; ++j) cnt += (dlens_i[j] > t) ? 1 : 0;
        nact[t] = cnt;
    }
}

// ---------------- zero entire output buffer ----------------
__global__ void k_zero(float4* __restrict__ p, long n4)
{
    long i = (long)blockIdx.x * 256 + threadIdx.x;
    if (i < n4) p[i] = make_float4(0.f, 0.f, 0.f, 0.f);
}

// ---------------- gather + fp32->bf16 convert enc rows into sorted order ----------------
__global__ void k_cvt_enc(const float* __restrict__ enc, const int* __restrict__ sort_ind,
                          u16* __restrict__ A_bf)
{
    int row = blockIdx.y;                 // 0..12543  (b*196+p sorted)
    int b = row / 196, p = row - b * 196;
    int e4 = (blockIdx.x * 256 + threadIdx.x) * 4;   // 0..2044
    const float* src = enc + ((long)sort_ind[b] * 196 + p) * E_ + e4;
    float4 v = *(const float4*)src;
    unsigned lo = (unsigned)f2bf(v.x) | ((unsigned)f2bf(v.y) << 16);
    unsigned hi = (unsigned)f2bf(v.z) | ((unsigned)f2bf(v.w) << 16);
    uint2 pk; pk.x = lo; pk.y = hi;
    *(uint2*)(A_bf + (long)row * E_ + e4) = pk;
}

// ---------------- tiled transpose + convert: fp32 [K][N] -> bf16 [Np][Kp] (pads=0) ----
__global__ void k_transpose(const float* __restrict__ src, u16* __restrict__ dst,
                            int K, int N, int Kp, int Np)
{
    __shared__ float tile[32][33];
    int n0 = blockIdx.x * 32, k0 = blockIdx.y * 32;
    int tx = threadIdx.x, ty = threadIdx.y;   // (32,8)
    for (int r = ty; r < 32; r += 8) {
        int k = k0 + r, n = n0 + tx;
        tile[r][tx] = (k < K && n < N) ? src[(long)k * N + n] : 0.f;
    }
    __syncthreads();
    for (int r = ty; r < 32; r += 8) {
        int n = n0 + r, k = k0 + tx;
        if (n < Np && k < Kp) dst[(long)n * Kp + k] = f2bf(tile[tx][r]);
    }
}

// ---------------- enc mean -> dec_in_bf cols [0,2048) ----------------
__global__ void k_encmean(const float* __restrict__ enc, const int* __restrict__ sort_ind,
                          u16* __restrict__ dec_in)
{
    int b = blockIdx.y;
    int e = blockIdx.x * 256 + threadIdx.x;   // < 2048
    int orig = sort_ind[b];
    const float* src = enc + (long)orig * P_ * E_ + e;
    float s = 0.f;
    for (int p = 0; p < P_; ++p) s += src[(long)p * E_];
    dec_in[(long)b * XK_ + e] = f2bf(s * (1.f / 196.f));
}

// ---------------- context -> dec_in_bf cols [2048,2560), pad 0 ----------------
__global__ void k_ctx(const float* __restrict__ arts, const float* __restrict__ W_par,
                      const float* __restrict__ b_par, const int* __restrict__ sort_ind,
                      u16* __restrict__ dec_in)
{
    int b = blockIdx.y;
    int k = blockIdx.x * 256 + threadIdx.x;   // < 512
    if (k >= 512) return;
    float s = 0.f;
    if (k < ADL_) {
        int orig = sort_ind[b];
        const float* ar = arts + (long)orig * AML_;
        s = b_par[k];
        for (int m = 0; m < AML_; ++m) s = fmaf(ar[m], W_par[m * ADL_ + k], s);
    }
    dec_in[(long)b * XK_ + E_ + k] = f2bf(s);
}

// ---------------- emb gather for ALL timesteps (loop-invariant) ----------------
__global__ void k_emb_all(const float* __restrict__ E_emb, const int* __restrict__ caps_s,
                          u16* __restrict__ emb_all)
{
    int t = blockIdx.x;   // 0..28
    int b = blockIdx.y;
    int tok = caps_s[b * L_ + t];
    for (int k = threadIdx.x; k < EMB_; k += 256)
        emb_all[((long)t * B_ + b) * EMB_ + k] = f2bf(E_emb[(long)tok * EMB_ + k]);
}

// ---------------- att1 MFMA ----------------
__global__ void __launch_bounds__(256) k_att1_mfma(
    const u16* __restrict__ A, const u16* __restrict__ W,
    const float* __restrict__ bias, u16* __restrict__ Yb)
{
    int w = threadIdx.x >> 6, lane = threadIdx.x & 63;
    int lr = lane & 15, lk = (lane >> 4) * 8;
    int n0 = blockIdx.x * 256 + w * 64;
    int r0 = blockIdx.y * 64;
    f32x4 acc[4][4];
#pragma unroll
    for (int i = 0; i < 4; ++i)
#pragma unroll
        for (int j = 0; j < 4; ++j) acc[i][j] = (f32x4){0.f, 0.f, 0.f, 0.f};
    const u16* ap = A + (long)(r0 + lr) * E_ + lk;
    const u16* wp = W + (long)(n0 + lr) * E_ + lk;
    for (int k = 0; k < E_; k += 32) {
        bf16x8 af[4], bf[4];
#pragma unroll
        for (int mt = 0; mt < 4; ++mt) af[mt] = *(const bf16x8*)(ap + (long)mt * 16 * E_ + k);
#pragma unroll
        for (int nt = 0; nt < 4; ++nt) bf[nt] = *(const bf16x8*)(wp + (long)nt * 16 * E_ + k);
#pragma unroll
        for (int mt = 0; mt < 4; ++mt)
#pragma unroll
            for (int nt = 0; nt < 4; ++nt)
                acc[mt][nt] = __builtin_amdgcn_mfma_f32_16x16x32_bf16(af[mt], bf[nt], acc[mt][nt], 0, 0, 0);
    }
#pragma unroll
    for (int mt = 0; mt < 4; ++mt) {
#pragma unroll
        for (int nt = 0; nt < 4; ++nt) {
            int n = n0 + nt * 16 + lr;
            float bv = (n < A_) ? bias[n] : 0.f;
#pragma unroll
            for (int j = 0; j < 4; ++j) {
                int row = r0 + mt * 16 + (lane >> 4) * 4 + j;
                u16 outv = (n < A_) ? f2bf(acc[mt][nt][j] + bv) : (u16)0;
                Yb[(long)row * 1024 + n] = outv;
            }
        }
    }
}

// ---------------- skinny MFMA (h0/c0) ----------------
template <int ACT, int OUT, int PADZ>
__global__ void __launch_bounds__(256) k_skinny(
    const u16* __restrict__ A1, const u16* __restrict__ W1, int K1,
    const float* __restrict__ bias1, void* __restrict__ Yv,
    long ldY, long offY, int Nmax,
    const int* __restrict__ nact, int t)
{
    int Bact = (t >= 0) ? nact[t] : B_;
    if (Bact <= 0) return;
    int mmax = (Bact + 15) >> 4;
    int w = threadIdx.x >> 6, lane = threadIdx.x & 63;
    int lr = lane & 15, lk = (lane >> 4) * 8;
    int n0 = blockIdx.x * 64 + w * 16;
    f32x4 acc[4];
#pragma unroll
    for (int m = 0; m < 4; ++m) acc[m] = (f32x4){0.f, 0.f, 0.f, 0.f};

    int n = n0 + lr;
    int nc = n < Nmax ? n : Nmax - 1;
    const u16* a1p = A1 + (long)lr * K1 + lk;
    const u16* w1p = W1 + (long)nc * K1 + lk;
    for (int k = 0; k < K1; k += 32) {
        bf16x8 bw = *(const bf16x8*)(w1p + k);
#pragma unroll
        for (int m = 0; m < 4; ++m)
            if (m < mmax) {
                bf16x8 aw = *(const bf16x8*)(a1p + (long)m * 16 * K1 + k);
                acc[m] = __builtin_amdgcn_mfma_f32_16x16x32_bf16(aw, bw, acc[m], 0, 0, 0);
            }
    }
    float bv = (n < Nmax) ? bias1[n] : 0.f;
#pragma unroll
    for (int m = 0; m < 4; ++m) {
        if (m < mmax) {
#pragma unroll
            for (int j = 0; j < 4; ++j) {
                int b = m * 16 + (lane >> 4) * 4 + j;
                if (b < Bact) {
                    float v = acc[m][j] + bv;
                    if (ACT == 1) v = sigf(v);
                    if (n < Nmax) {
                        if (OUT == 1) ((u16*)Yv)[(long)b * ldY + offY + n] = f2bf(v);
                        else          ((float*)Yv)[(long)b * ldY + offY + n] = v;
                    } else if (PADZ) {
                        if (OUT == 1) ((u16*)Yv)[(long)b * ldY + offY + n] = 0;
                        else          ((float*)Yv)[(long)b * ldY + offY + n] = 0.f;
                    }
                }
            }
        }
    }
}

// ---------------- att2+fb, K-split x2 into partial buffers ----------------
__global__ void __launch_bounds__(256) k_att2fb(
    const u16* __restrict__ h_bf, const u16* __restrict__ WT_dec,
    const u16* __restrict__ WT_fb, const float* __restrict__ b_dec,
    const float* __restrict__ b_fb, float* __restrict__ att2p,
    float* __restrict__ fbp, const int* __restrict__ nact, int t)
{
    int Bact = nact[t];
    if (Bact <= 0) return;
    int mmax = (Bact + 15) >> 4;
    int kh = blockIdx.x >= 48;
    int nb = blockIdx.x - (kh ? 48 : 0);
    int isfb = nb >= 16;
    const u16* W = isfb ? WT_fb : WT_dec;
    const float* bias = isfb ? b_fb : b_dec;
    int Nmax = isfb ? E_ : A_;
    int nb2 = isfb ? nb - 16 : nb;
    long ldY = isfb ? (long)E_ : 1024L;
    float* Y = (isfb ? fbp : att2p) + (long)kh * B_ * ldY;

    int w = threadIdx.x >> 6, lane = threadIdx.x & 63;
    int lr = lane & 15, lk = (lane >> 4) * 8;
    int n = nb2 * 64 + w * 16 + lr;
    int nc = n < Nmax ? n : Nmax - 1;
    int k0 = kh * 512;
    f32x4 acc[4];
#pragma unroll
    for (int m = 0; m < 4; ++m) acc[m] = (f32x4){0.f, 0.f, 0.f, 0.f};
    const u16* ap = h_bf + (long)lr * 1024 + k0 + lk;
    const u16* wp = W + (long)nc * 1024 + k0 + lk;
    for (int k = 0; k < 512; k += 32) {
        bf16x8 bw = *(const bf16x8*)(wp + k);
#pragma unroll
        for (int m = 0; m < 4; ++m)
            if (m < mmax) {
                bf16x8 aw = *(const bf16x8*)(ap + (long)m * 16 * 1024 + k);
                acc[m] = __builtin_amdgcn_mfma_f32_16x16x32_bf16(aw, bw, acc[m], 0, 0, 0);
            }
    }
    if (n >= Nmax) return;
    float bv = (kh == 0) ? bias[n] : 0.f;
#pragma unroll
    for (int m = 0; m < 4; ++m) {
        if (m < mmax) {
#pragma unroll
            for (int j = 0; j < 4; ++j) {
                int b = m * 16 + (lane >> 4) * 4 + j;
                if (b < Bact) Y[(long)b * ldY + n] = acc[m][j] + bv;
            }
        }
    }
}

// ---------------- scores: relu(att1_bf + att2p0 + att2p1) @ W_full + b_full ----------------
__global__ void k_scores(const u16* __restrict__ att1, const float* __restrict__ att2p,
                         const float* __restrict__ W_full, const float* __restrict__ b_full,
                         float* __restrict__ scores, const int* __restrict__ nact, int t)
{
    int b = blockIdx.y;
    if (b >= nact[t]) return;
    int wv = threadIdx.x >> 6;
    int lane = threadIdx.x & 63;
    int p = blockIdx.x * 4 + wv;   // 49*4 = 196
    const u16* a1 = att1 + ((long)b * P_ + p) * 1024;
    const float* a20 = att2p + (long)b * 1024;
    const float* a21 = att2p + (long)B_ * 1024 + (long)b * 1024;
    float acc = 0.f;
    for (int j2 = lane; j2 < 506; j2 += 64) {
        unsigned pk = *(const unsigned*)(a1 + 2 * j2);
        float2 p0 = *(const float2*)(a20 + 2 * j2);
        float2 p1 = *(const float2*)(a21 + 2 * j2);
        float2 wv2 = *(const float2*)(W_full + 2 * j2);
        float v0 = bf2f((u16)(pk & 0xFFFF)) + p0.x + p1.x;
        float v1 = bf2f((u16)(pk >> 16)) + p0.y + p1.y;
        v0 = v0 > 0.f ? v0 : 0.f;
        v1 = v1 > 0.f ? v1 : 0.f;
        acc = fmaf(v0, wv2.x, acc);
        acc = fmaf(v1, wv2.y, acc);
    }
    for (int m = 32; m >= 1; m >>= 1) acc += __shfl_xor(acc, m);
    if (lane == 0) scores[b * P_ + p] = acc + b_full[0];
}

// ---------------- awe + local softmax (+alphas) ----------------
// grid (9, 64): blocks 0-7 -> awe_buf cols; block 8 -> alphas_out
__global__ void __launch_bounds__(256) k_awe_x(
    const u16* __restrict__ A_bf, const float* __restrict__ scores,
    const float* __restrict__ fbp, u16* __restrict__ awe_buf,
    float* __restrict__ alphas_out, const int* __restrict__ nact, int t)
{
    int b = blockIdx.y;
    if (b >= nact[t]) return;
    int tid = threadIdx.x;
    int w = tid >> 6, lane = tid & 63;
    __shared__ float al[P_];
    __shared__ float red[4];
    float v = (tid < P_) ? scores[b * P_ + tid] : -1e30f;
    float m = v;
    for (int s = 32; s >= 1; s >>= 1) m = fmaxf(m, __shfl_xor(m, s));
    if (lane == 0) red[w] = m;
    __syncthreads();
    m = fmaxf(fmaxf(red[0], red[1]), fmaxf(red[2], red[3]));
    float e = (tid < P_) ? __expf(v - m) : 0.f;
    float s_ = e;
    for (int s = 32; s >= 1; s >>= 1) s_ += __shfl_xor(s_, s);
    __syncthreads();
    if (lane == 0) red[w] = s_;
    __syncthreads();
    s_ = red[0] + red[1] + red[2] + red[3];
    if (tid < P_) al[tid] = e / s_;
    __syncthreads();

    if (blockIdx.x < 8) {
        int e0 = blockIdx.x * 256 + tid;
        const u16* src = A_bf + (long)b * P_ * E_ + e0;
        float s0 = 0.f, s1 = 0.f, s2 = 0.f, s3 = 0.f;
        for (int p = 0; p < P_; p += 4) {
            s0 = fmaf(al[p],     bf2f(src[(long)p * E_]), s0);
            s1 = fmaf(al[p + 1], bf2f(src[(long)(p + 1) * E_]), s1);
            s2 = fmaf(al[p + 2], bf2f(src[(long)(p + 2) * E_]), s2);
            s3 = fmaf(al[p + 3], bf2f(src[(long)(p + 3) * E_]), s3);
        }
        float g = sigf(fbp[(long)b * E_ + e0] + fbp[(long)(B_ + b) * E_ + e0]);
        awe_buf[(long)b * E_ + e0] = f2bf((s0 + s1 + s2 + s3) * g);
    } else {
        if (tid < P_) alphas_out[((long)b * T_ + t) * P_ + tid] = al[tid];
    }
}

// ---------------- gates GEMM partials: grid (64, 2), wave = quadrant, K-split across y ----
// gpart[kh][b][q*1024 + n]
__global__ void __launch_bounds__(256) k_gates(
    const u16* __restrict__ emb_t, const u16* __restrict__ awe,
    const u16* __restrict__ h_old, const u16* __restrict__ WT_ih,
    const u16* __restrict__ WT_hh, float* __restrict__ gpart,
    const int* __restrict__ nact, int t)
{
    int Bact = nact[t];
    if (Bact <= 0) return;
    int mmax = (Bact + 15) >> 4;
    int q = threadIdx.x >> 6;
    int lane = threadIdx.x & 63;
    int lr = lane & 15, lk = (lane >> 4) * 8;
    int kh = blockIdx.y;
    int n = blockIdx.x * 16 + lr;          // 0..1023
    int nc = n < D_ ? n : D_ - 1;
    f32x4 acc[4];
#pragma unroll
    for (int m = 0; m < 4; ++m) acc[m] = (f32x4){0.f, 0.f, 0.f, 0.f};
    const u16* wih = WT_ih + ((long)q * D_ + nc) * XK_;
    const u16* whh = WT_hh + ((long)q * D_ + nc) * 1024;

    if (kh == 0) {
        // emb segment: W_ih rows 0..512
        const u16* ap = emb_t + (long)lr * EMB_ + lk;
        for (int k = 0; k < EMB_; k += 32) {
            bf16x8 bw = *(const bf16x8*)(wih + k);
#pragma unroll
            for (int m = 0; m < 4; ++m)
                if (m < mmax) {
                    bf16x8 aw = *(const bf16x8*)(ap + (long)m * 16 * EMB_ + k);
                    acc[m] = __builtin_amdgcn_mfma_f32_16x16x32_bf16(aw, bw, acc[m], 0, 0, 0);
                }
        }
        // awe cols 0..1280: W_ih rows 512..1792
        const u16* ap2 = awe + (long)lr * E_ + lk;
        const u16* w2 = wih + EMB_;
        for (int k = 0; k < 1280; k += 32) {
            bf16x8 bw = *(const bf16x8*)(w2 + k);
#pragma unroll
            for (int m = 0; m < 4; ++m)
                if (m < mmax) {
                    bf16x8 aw = *(const bf16x8*)(ap2 + (long)m * 16 * E_ + k);
                    acc[m] = __builtin_amdgcn_mfma_f32_16x16x32_bf16(aw, bw, acc[m], 0, 0, 0);
                }
        }
    } else {
        // awe cols 1280..2048: W_ih rows 1792..2560
        const u16* ap2 = awe + (long)lr * E_ + 1280 + lk;
        const u16* w2 = wih + 1792;
        for (int k = 0; k < 768; k += 32) {
            bf16x8 bw = *(const bf16x8*)(w2 + k);
#pragma unroll
            for (int m = 0; m < 4; ++m)
                if (m < mmax) {
                    bf16x8 aw = *(const bf16x8*)(ap2 + (long)m * 16 * E_ + k);
                    acc[m] = __builtin_amdgcn_mfma_f32_16x16x32_bf16(aw, bw, acc[m], 0, 0, 0);
                }
        }
        // h segment: W_hh rows 0..1024
        const u16* ap3 = h_old + (long)lr * 1024 + lk;
        for (int k = 0; k < 1024; k += 32) {
            bf16x8 bw = *(const bf16x8*)(whh + k);
#pragma unroll
            for (int m = 0; m < 4; ++m)
                if (m < mmax) {
                    bf16x8 aw = *(const bf16x8*)(ap3 + (long)m * 16 * 1024 + k);
                    acc[m] = __builtin_amdgcn_mfma_f32_16x16x32_bf16(aw, bw, acc[m], 0, 0, 0);
                }
        }
    }
#pragma unroll
    for (int m = 0; m < 4; ++m) {
        if (m < mmax) {
#pragma unroll
            for (int j = 0; j < 4; ++j) {
                int bb = m * 16 + (lane >> 4) * 4 + j;
                if (bb < Bact)
                    gpart[((long)kh * B_ + bb) * 4096 + q * 1024 + n] = acc[m][j];
            }
        }
    }
}

// ---------------- reduce partials + LSTM pointwise; h -> h_all slot t+1 ----------------
__global__ void k_lstm_red(const float* __restrict__ gpart, const float* __restrict__ b_ih,
                           const float* __restrict__ b_hh, float* __restrict__ cbuf,
                           u16* __restrict__ h_new, const int* __restrict__ nact, int t)
{
    int b = blockIdx.y;
    if (b >= nact[t]) return;
    int n = blockIdx.x * 256 + threadIdx.x;   // grid.x = 4
    if (n >= D_) return;
    const float* g0 = gpart + (long)b * 4096;
    const float* g1 = gpart + (long)(B_ + b) * 4096;
    float gi = g0[n]        + g1[n]        + b_ih[n]          + b_hh[n];
    float gf = g0[1024 + n] + g1[1024 + n] + b_ih[D_ + n]     + b_hh[D_ + n];
    float gg = g0[2048 + n] + g1[2048 + n] + b_ih[2 * D_ + n] + b_hh[2 * D_ + n];
    float go = g0[3072 + n] + g1[3072 + n] + b_ih[3 * D_ + n] + b_hh[3 * D_ + n];
    float c = cbuf[(long)b * 1024 + n];
    float cn = sigf(gf) * c + sigf(gi) * tanhf_fast(gg);
    float hn = sigf(go) * tanhf_fast(cn);
    cbuf[(long)b * 1024 + n] = cn;
    h_new[(long)b * 1024 + n] = f2bf(hn);
}

// ---------------- batched FC over all steps: h_all[1..29] @ W_fc -> preds ----------------
// grid (40, 29)
__global__ void __launch_bounds__(256) k_fc_all(
    const u16* __restrict__ h_all, const u16* __restrict__ W,
    const float* __restrict__ bias, float* __restrict__ out_preds,
    const int* __restrict__ nact)
{
    int tslot = blockIdx.y;              // 0..28
    int Bact = nact[tslot];
    if (Bact <= 0) return;
    int mmax = (Bact + 15) >> 4;
    int w = threadIdx.x >> 6, lane = threadIdx.x & 63;
    int lr = lane & 15, lk = (lane >> 4) * 8;
    int n0 = blockIdx.x * 256 + w * 64;
    f32x4 acc[4][4];
#pragma unroll
    for (int i = 0; i < 4; ++i)
#pragma unroll
        for (int j = 0; j < 4; ++j) acc[i][j] = (f32x4){0.f, 0.f, 0.f, 0.f};
    const u16* ap = h_all + ((long)(tslot + 1) * B_ + lr) * 1024 + lk;
    int ncl[4];
#pragma unroll
    for (int nt = 0; nt < 4; ++nt) {
        int n = n0 + nt * 16 + lr;
        ncl[nt] = n < V_ ? n : V_ - 1;
    }
    for (int k = 0; k < 1024; k += 32) {
        bf16x8 af[4], bf[4];
#pragma unroll
        for (int mt = 0; mt < 4; ++mt)
            if (mt < mmax) af[mt] = *(const bf16x8*)(ap + (long)mt * 16 * 1024 + k);
#pragma unroll
        for (int nt = 0; nt < 4; ++nt) bf[nt] = *(const bf16x8*)(W + (long)ncl[nt] * 1024 + lk + k);
#pragma unroll
        for (int mt = 0; mt < 4; ++mt)
            if (mt < mmax)
#pragma unroll
                for (int nt = 0; nt < 4; ++nt)
                    acc[mt][nt] = __builtin_amdgcn_mfma_f32_16x16x32_bf16(af[mt], bf[nt], acc[mt][nt], 0, 0, 0);
    }
#pragma unroll
    for (int nt = 0; nt < 4; ++nt) {
        int n = n0 + nt * 16 + lr;
        if (n >= V_) continue;
        float bv = bias[n];
#pragma unroll
        for (int mt = 0; mt < 4; ++mt) {
            if (mt < mmax) {
#pragma unroll
                for (int j = 0; j < 4; ++j) {
                    int b = mt * 16 + (lane >> 4) * 4 + j;
                    if (b < Bact)
                        out_preds[(long)b * T_ * V_ + (long)tslot * V_ + n] = acc[mt][nt][j] + bv;
                }
            }
        }
    }
}

extern "C" void kernel_launch(void* const* d_in, const int* in_sizes, int n_in,
                              void* d_out, int out_size, void* d_ws, size_t ws_size,
                              hipStream_t stream)
{
    const float* enc    = (const float*)d_in[0];
    const int*   caps   = (const int*)d_in[1];
    const int*   clen   = (const int*)d_in[2];
    const float* arts   = (const float*)d_in[3];
    const float* E_emb  = (const float*)d_in[6];
    const float* W_par  = (const float*)d_in[7];
    const float* b_par  = (const float*)d_in[8];
    const float* W_enc  = (const float*)d_in[9];
    const float* b_enc  = (const float*)d_in[10];
    const float* W_dec  = (const float*)d_in[11];
    const float* b_dec  = (const float*)d_in[12];
    const float* W_full = (const float*)d_in[13];
    const float* b_full = (const float*)d_in[14];
    const float* W_h    = (const float*)d_in[15];
    const float* b_h    = (const float*)d_in[16];
    const float* W_c    = (const float*)d_in[17];
    const float* b_c    = (const float*)d_in[18];
    const float* W_fb   = (const float*)d_in[19];
    const float* b_fb   = (const float*)d_in[20];
    const float* W_ih   = (const float*)d_in[21];
    const float* b_ih   = (const float*)d_in[22];
    const float* W_hh   = (const float*)d_in[23];
    const float* b_hh   = (const float*)d_in[24];
    const float* W_fc   = (const float*)d_in[25];
    const float* b_fc   = (const float*)d_in[26];

    float* out = (float*)d_out;
    float* out_preds  = out;
    float* out_caps   = out + (long)B_ * T_ * V_;
    float* out_dlens  = out_caps + B_ * L_;
    float* out_alphas = out_dlens + B_;
    float* out_sind   = out_alphas + (long)B_ * T_ * P_;

    // workspace layout (float units, 64-aligned)
    float* ws = (float*)d_ws;
    long o = 0;
    auto alloc = [&](long n) { long r = o; o += (n + 63) & ~63L; return r; };
    long o_ints   = alloc(2176);
    long o_decin  = alloc((long)B_ * XK_ / 2);
    long o_hall   = alloc((long)(T_ + 1) * B_ * 1024 / 2);   // bf16 [30][64][1024]
    long o_emball = alloc((long)T_ * B_ * EMB_ / 2);         // bf16 [29][64][512]
    long o_awe    = alloc((long)B_ * E_ / 2);                // bf16 [64][2048]
    long o_c      = alloc((long)B_ * 1024);
    long o_att2p  = alloc((long)2 * B_ * 1024);
    long o_fbp    = alloc((long)2 * B_ * E_);
    long o_gpart  = alloc((long)2 * B_ * 4096);
    long o_scores = alloc((long)B_ * P_);
    long o_Abf    = alloc((long)12544 * E_ / 2);
    long o_att1   = alloc((long)12544 * 1024 / 2);
    long o_wtenc  = alloc((long)1024 * 2048 / 2);
    long o_wtdec  = alloc((long)1024 * 1024 / 2);
    long o_wtfb   = alloc((long)2048 * 1024 / 2);
    long o_wtih   = alloc((long)4096 * 2560 / 2);
    long o_wthh   = alloc((long)4096 * 1024 / 2);
    long o_wtfc   = alloc((long)10048 * 1024 / 2);

    int* sort_ind = (int*)(ws + o_ints);
    int* dlens_i  = sort_ind + 64;
    int* nact     = dlens_i + 64;
    int* caps_s   = nact + 32;
    u16*   dec_in  = (u16*)(ws + o_decin);
    u16*   h_all   = (u16*)(ws + o_hall);
    u16*   emb_all = (u16*)(ws + o_emball);
    u16*   awe_buf = (u16*)(ws + o_awe);
    float* cbuf   = ws + o_c;
    float* att2p  = ws + o_att2p;
    float* fbp    = ws + o_fbp;
    float* gpart  = ws + o_gpart;
    float* scores = ws + o_scores;
    u16*   A_bf   = (u16*)(ws + o_Abf);
    u16*   att1   = (u16*)(ws + o_att1);
    u16*   WT_enc = (u16*)(ws + o_wtenc);
    u16*   WT_dec = (u16*)(ws + o_wtdec);
    u16*   WT_fb  = (u16*)(ws + o_wtfb);
    u16*   WT_ih  = (u16*)(ws + o_wtih);
    u16*   WT_hh  = (u16*)(ws + o_wthh);
    u16*   WT_fc  = (u16*)(ws + o_wtfc);
    // transient: WT_h / WT_c live in att1's region (overwritten later by k_att1_mfma)
    u16*   WT_h   = att1;
    u16*   WT_c   = att1 + (long)1024 * XK_;

    long n4 = ((long)B_ * T_ * V_ + B_ * L_ + B_ + (long)B_ * T_ * P_ + B_) / 4;
    k_zero<<<dim3((unsigned)((n4 + 255) / 256)), 256, 0, stream>>>((float4*)d_out, n4);
    k_setup<<<1, 64, 0, stream>>>(clen, caps, out_caps, out_dlens, out_sind,
                                  sort_ind, dlens_i, nact, caps_s);

    k_encmean<<<dim3(8, 64), 256, 0, stream>>>(enc, sort_ind, dec_in);
    k_ctx<<<dim3(2, 64), 256, 0, stream>>>(arts, W_par, b_par, sort_ind, dec_in);
    k_emb_all<<<dim3(T_, 64), 256, 0, stream>>>(E_emb, caps_s, emb_all);

    dim3 tb(32, 8);
    k_transpose<<<dim3(1024/32, 2560/32), tb, 0, stream>>>(W_h, WT_h, 2548, 1012, 2560, 1024);
    k_transpose<<<dim3(1024/32, 2560/32), tb, 0, stream>>>(W_c, WT_c, 2548, 1012, 2560, 1024);
    // h0 -> h_all slot 0 (bf16, pad-zero cols), c0 -> cbuf (f32)
    k_skinny<0,1,1><<<dim3(16), 256, 0, stream>>>(dec_in, WT_h, XK_, b_h, h_all, 1024L, 0L, D_,
                                                  nact, -1);
    k_skinny<0,0,1><<<dim3(16), 256, 0, stream>>>(dec_in, WT_c, XK_, b_c, cbuf, 1024L, 0L, D_,
                                                  nact, -1);

    k_transpose<<<dim3(1024/32, 2048/32), tb, 0, stream>>>(W_enc, WT_enc, 2048, 1012, 2048, 1024);
    k_transpose<<<dim3(1024/32, 1024/32), tb, 0, stream>>>(W_dec, WT_dec, 1012, 1012, 1024, 1024);
    k_transpose<<<dim3(2048/32, 1024/32), tb, 0, stream>>>(W_fb, WT_fb, 1012, 2048, 1024, 2048);
    k_transpose<<<dim3(4096/32, 2560/32), tb, 0, stream>>>(W_ih, WT_ih, 2560, 4048, 2560, 4096);
    k_transpose<<<dim3(4096/32, 1024/32), tb, 0, stream>>>(W_hh, WT_hh, 1012, 4048, 1024, 4096);
    k_transpose<<<dim3(10048/32, 1024/32), tb, 0, stream>>>(W_fc, WT_fc, 1012, 10000, 1024, 10048);

    k_cvt_enc<<<dim3(2, 12544), 256, 0, stream>>>(enc, sort_ind, A_bf);
    k_att1_mfma<<<dim3(4, 196), 256, 0, stream>>>(A_bf, WT_enc, b_enc, att1);

    for (int t = 0; t < T_; ++t) {
        const u16* h_old = h_all + (long)t * B_ * 1024;
        u16* h_new = h_all + (long)(t + 1) * B_ * 1024;
        const u16* emb_t = emb_all + (long)t * B_ * EMB_;
        k_att2fb<<<dim3(96), 256, 0, stream>>>(h_old, WT_dec, WT_fb, b_dec, b_fb,
                                               att2p, fbp, nact, t);
        k_scores<<<dim3(49, 64), 256, 0, stream>>>(att1, att2p, W_full, b_full, scores, nact, t);
        k_awe_x<<<dim3(9, 64), 256, 0, stream>>>(A_bf, scores, fbp, awe_buf,
                                                 out_alphas, nact, t);
        k_gates<<<dim3(64, 2), 256, 0, stream>>>(emb_t, awe_buf, h_old, WT_ih, WT_hh,
                                                 gpart, nact, t);
        k_lstm_red<<<dim3(4, 64), 256, 0, stream>>>(gpart, b_ih, b_hh, cbuf, h_new, nact, t);
    }
    k_fc_all<<<dim3(40, T_), 256, 0, stream>>>(h_all, WT_fc, b_fc, out_preds, nact);
}